// Round 8
// baseline (31.317 us; speedup 1.0000x reference)
//
#include <hip/hip_runtime.h>
#include <math.h>

// Depthwise max-plus 5x5 correlation, pad=2, stride=1, dilation=1.
//   imgs: (8,32,256,256) f32, kernel: (32,1,5,5) f32, out same shape.
#define BB 8
#define CC 32
#define HH 256
#define WW 256
#define TR 16              // output rows per block
#define LR (TR + 4)        // staged LDS rows (2+2 vertical halo)
#define LW (WW + 4)        // LDS row: 2-pad | 256 | 2-pad  (260 floats)

typedef unsigned int u32;

// Block: 16 rows x 256 cols of one plane. 20 input rows staged to LDS via
// global_load_lds (1 instr = 1 KB row per wave). LDS rows are -inf padded
// left/right, so compute needs NO edge cndmasks and only 2 ds_read_b128
// per input row. Weights forced to SGPRs via readfirstlane. Target: <=64
// VGPR -> 8 waves/SIMD (LDS caps at 7 blocks/CU, ~87% occupancy).
__global__ __launch_bounds__(256, 8) void selconv_kernel(
    const float* __restrict__ imgs,
    const float* __restrict__ kern,
    float* __restrict__ out)
{
    __shared__ float lds[LR * LW];          // 20800 B

    const int t    = threadIdx.x;
    const int lane = t & 63;
    const int wv   = t >> 6;                // wave 0..3 (uniform)
    const int p    = blockIdx.x >> 4;       // plane b*C + c (uniform)
    const int rt   = blockIdx.x & 15;       // row tile (uniform)
    const int c    = p & (CC - 1);
    const int y0   = rt * TR;
    const int x    = lane * 4;

    const float NEG = -INFINITY;
    const float* plane = imgs + (size_t)p * (HH * WW);

    // ---- Stage 20 rows: wave wv stages LDS rows 5*wv .. 5*wv+4 ----
    if (rt != 0 && rt != 15) {
#pragma unroll
        for (int i = 0; i < 5; ++i) {
            const int L  = wv * 5 + i;                  // uniform
            const int iy = y0 - 2 + L;                  // in-bounds (interior)
            __builtin_amdgcn_global_load_lds(
                (const __attribute__((address_space(1))) u32*)(plane + iy * WW + x),
                (__attribute__((address_space(3))) u32*)(&lds[L * LW + 2]),
                16, 0, 0);
        }
    } else {
#pragma unroll
        for (int i = 0; i < 5; ++i) {
            const int L  = wv * 5 + i;
            const int iy = y0 - 2 + L;
            if (iy >= 0 && iy < HH) {                   // wave-uniform
                __builtin_amdgcn_global_load_lds(
                    (const __attribute__((address_space(1))) u32*)(plane + iy * WW + x),
                    (__attribute__((address_space(3))) u32*)(&lds[L * LW + 2]),
                    16, 0, 0);
            } else {
                *reinterpret_cast<float4*>(&lds[L * LW + 2 + x]) =
                    make_float4(NEG, NEG, NEG, NEG);
            }
        }
    }

    // Left/right -inf pads: 20 rows x 4 cells, threads 0..79 one cell each.
    if (t < LR * 4) {
        const int L = t >> 2;
        const int q = t & 3;
        const int col = (q < 2) ? q : (WW + q);          // 0,1,258,259
        lds[L * LW + col] = NEG;
    }

    // ---- Weights: force SGPRs (uniform values) ----
    float w[25];
    const float* kw = kern + c * 25;
#pragma unroll
    for (int i = 0; i < 25; ++i) {
        union { float f; int i; } u;
        u.f = kw[i];
        u.i = __builtin_amdgcn_readfirstlane(u.i);
        w[i] = u.f;
    }

    __syncthreads();   // drains global_load_lds (vmcnt) + ds_writes (lgkmcnt)

    // ---- Compute: wave wv owns output rows (rel) 4*wv .. 4*wv+3 ----
    const int or0 = wv * 4;

    float acc[4][4];
#pragma unroll
    for (int r = 0; r < 4; ++r)
#pragma unroll
        for (int j = 0; j < 4; ++j) acc[r][j] = NEG;

    // Input row (rel) or0+dl feeds output rows or0+dl-ky for ky=0..4.
    // LDS col x+k = input col x+k-2, so output col x+j taps v[j..j+4].
#pragma unroll
    for (int dl = 0; dl < 8; ++dl) {
        const float* lrow = &lds[(or0 + dl) * LW];
        const float4 a = *reinterpret_cast<const float4*>(lrow + x);
        const float4 b = *reinterpret_cast<const float4*>(lrow + x + 4);
        const float v[8] = {a.x, a.y, a.z, a.w, b.x, b.y, b.z, b.w};
#pragma unroll
        for (int ky = 0; ky < 5; ++ky) {
            const int r = dl - ky;               // compile-time after unroll
            if (r < 0 || r > 3) continue;        // DCE'd
#pragma unroll
            for (int j = 0; j < 4; ++j) {
                const float s0 = v[j + 0] + w[ky * 5 + 0];
                const float s1 = v[j + 1] + w[ky * 5 + 1];
                const float s2 = v[j + 2] + w[ky * 5 + 2];
                const float s3 = v[j + 3] + w[ky * 5 + 3];
                const float s4 = v[j + 4] + w[ky * 5 + 4];
                // v_max3(s0,s1,s2), v_max3(s3,s4,acc), v_max
                acc[r][j] = fmaxf(fmaxf(fmaxf(s0, s1), s2),
                                  fmaxf(fmaxf(s3, s4), acc[r][j]));
            }
        }
    }

    float* op = out + (size_t)p * (HH * WW) + (y0 + or0) * WW + x;
#pragma unroll
    for (int r = 0; r < 4; ++r) {
        *reinterpret_cast<float4*>(op + r * WW) =
            make_float4(acc[r][0], acc[r][1], acc[r][2], acc[r][3]);
    }
}

extern "C" void kernel_launch(void* const* d_in, const int* in_sizes, int n_in,
                              void* d_out, int out_size, void* d_ws, size_t ws_size,
                              hipStream_t stream)
{
    const float* imgs = (const float*)d_in[0];
    const float* kern = (const float*)d_in[1];
    float* out = (float*)d_out;

    // 256 planes * 16 row-tiles = 4096 blocks x 256 threads
    const int blocks = BB * CC * (HH / TR);
    selconv_kernel<<<blocks, 256, 0, stream>>>(imgs, kern, out);
}

// Round 9
// 29.888 us; speedup vs baseline: 1.0478x; 1.0478x over previous
//
#include <hip/hip_runtime.h>
#include <math.h>

// Depthwise max-plus 5x5 correlation, pad=2, stride=1, dilation=1.
//   imgs: (8,32,256,256) f32, kernel: (32,1,5,5) f32, out same shape.
#define BB 8
#define CC 32
#define HH 256
#define WW 256
#define TR 16              // output rows per block
#define LR (TR + 4)        // staged LDS rows (2+2 vertical halo)
#define LW (WW + 4)        // LDS row: 2-pad | 256 | 2-pad

typedef unsigned int u32;
typedef float f32x2 __attribute__((ext_vector_type(2)));

__device__ __forceinline__ f32x2 pmax2(f32x2 a, f32x2 b) {
    return f32x2{fmaxf(a.x, b.x), fmaxf(a.y, b.y)};   // -> v_pk_max_f32
}

// R8 skeleton (LDS stage + padded rows + SGPR weights) with ROW-PAIR PACKED
// compute: output rows (2P,2P+1) consume input row dl with kernel rows
// (d, d-1), d = dl-2P. One v_pk_add_f32 (input broadcast via op_sel, weight
// pair in SGPRs) + v_pk_max_f32 chain covers 2 rows/tap -> ~30% issue cut.
__global__ __launch_bounds__(256) void selconv_kernel(
    const float* __restrict__ imgs,
    const float* __restrict__ kern,
    float* __restrict__ out)
{
    __shared__ float lds[LR * LW];          // 20800 B -> 7 blocks/CU

    const int t    = threadIdx.x;
    const int lane = t & 63;
    const int wv   = t >> 6;                // wave 0..3 (uniform)
    const int p    = blockIdx.x >> 4;       // plane b*C + c (uniform)
    const int rt   = blockIdx.x & 15;       // row tile (uniform)
    const int c    = p & (CC - 1);
    const int y0   = rt * TR;
    const int x    = lane * 4;

    const float NEG = -INFINITY;
    const float* plane = imgs + (size_t)p * (HH * WW);

    // ---- Stage 20 rows: wave wv stages LDS rows 5*wv .. 5*wv+4 ----
    if (rt != 0 && rt != 15) {
#pragma unroll
        for (int i = 0; i < 5; ++i) {
            const int L  = wv * 5 + i;
            const int iy = y0 - 2 + L;
            __builtin_amdgcn_global_load_lds(
                (const __attribute__((address_space(1))) u32*)(plane + iy * WW + x),
                (__attribute__((address_space(3))) u32*)(&lds[L * LW + 2]),
                16, 0, 0);
        }
    } else {
#pragma unroll
        for (int i = 0; i < 5; ++i) {
            const int L  = wv * 5 + i;
            const int iy = y0 - 2 + L;
            if (iy >= 0 && iy < HH) {
                __builtin_amdgcn_global_load_lds(
                    (const __attribute__((address_space(1))) u32*)(plane + iy * WW + x),
                    (__attribute__((address_space(3))) u32*)(&lds[L * LW + 2]),
                    16, 0, 0);
            } else {
                *reinterpret_cast<float4*>(&lds[L * LW + 2 + x]) =
                    make_float4(NEG, NEG, NEG, NEG);
            }
        }
    }

    // Left/right -inf pads: 20 rows x 4 cells.
    if (t < LR * 4) {
        const int L = t >> 2;
        const int q = t & 3;
        const int col = (q < 2) ? q : (WW + q);          // 0,1,258,259
        lds[L * LW + col] = NEG;
    }

    // ---- Weights -> SGPRs; pairs wp[m][k] = {w[(m+1)*5+k], w[m*5+k]} ----
    float w[25];
    const float* kw = kern + c * 25;
#pragma unroll
    for (int i = 0; i < 25; ++i) {
        union { float f; int i; } u;
        u.f = kw[i];
        u.i = __builtin_amdgcn_readfirstlane(u.i);
        w[i] = u.f;
    }
    f32x2 wp[4][5];
#pragma unroll
    for (int m = 0; m < 4; ++m)
#pragma unroll
        for (int k = 0; k < 5; ++k)
            wp[m][k] = f32x2{w[(m + 1) * 5 + k], w[m * 5 + k]};

    __syncthreads();

    // ---- Compute: wave wv owns output rows (rel) 4*wv .. 4*wv+3 ----
    const int or0 = wv * 4;

    // acc2[P][j] = {acc[row 2P][j], acc[row 2P+1][j]}
    f32x2 acc2[2][4];
#pragma unroll
    for (int P = 0; P < 2; ++P)
#pragma unroll
        for (int j = 0; j < 4; ++j) acc2[P][j] = f32x2{NEG, NEG};

#pragma unroll
    for (int dl = 0; dl < 8; ++dl) {
        const float* lrow = &lds[(or0 + dl) * LW];
        const float4 a = *reinterpret_cast<const float4*>(lrow + x);
        const float4 b = *reinterpret_cast<const float4*>(lrow + x + 4);
        const float v[8] = {a.x, a.y, a.z, a.w, b.x, b.y, b.z, b.w};

#pragma unroll
        for (int P = 0; P < 2; ++P) {
            const int d = dl - 2 * P;              // compile-time after unroll
            if (d >= 1 && d <= 4) {
                const int m = d - 1;
#pragma unroll
                for (int j = 0; j < 4; ++j) {
                    f32x2 t0 = f32x2{v[j + 0], v[j + 0]} + wp[m][0];
                    f32x2 t1 = f32x2{v[j + 1], v[j + 1]} + wp[m][1];
                    f32x2 t2 = f32x2{v[j + 2], v[j + 2]} + wp[m][2];
                    f32x2 t3 = f32x2{v[j + 3], v[j + 3]} + wp[m][3];
                    f32x2 t4 = f32x2{v[j + 4], v[j + 4]} + wp[m][4];
                    f32x2 mx = pmax2(pmax2(pmax2(t0, t1), pmax2(t2, t3)), t4);
                    acc2[P][j] = pmax2(acc2[P][j], mx);
                }
            } else if (d == 0) {                   // row 2P, ky = 0
#pragma unroll
                for (int j = 0; j < 4; ++j) {
                    const float s0 = v[j + 0] + w[0];
                    const float s1 = v[j + 1] + w[1];
                    const float s2 = v[j + 2] + w[2];
                    const float s3 = v[j + 3] + w[3];
                    const float s4 = v[j + 4] + w[4];
                    acc2[P][j].x = fmaxf(fmaxf(fmaxf(s0, s1), s2),
                                         fmaxf(fmaxf(s3, s4), acc2[P][j].x));
                }
            } else if (d == 5) {                   // row 2P+1, ky = 4
#pragma unroll
                for (int j = 0; j < 4; ++j) {
                    const float s0 = v[j + 0] + w[20];
                    const float s1 = v[j + 1] + w[21];
                    const float s2 = v[j + 2] + w[22];
                    const float s3 = v[j + 3] + w[23];
                    const float s4 = v[j + 4] + w[24];
                    acc2[P][j].y = fmaxf(fmaxf(fmaxf(s0, s1), s2),
                                         fmaxf(fmaxf(s3, s4), acc2[P][j].y));
                }
            }
        }
    }

    float* op = out + (size_t)p * (HH * WW) + (y0 + or0) * WW + x;
    *reinterpret_cast<float4*>(op + 0 * WW) =
        make_float4(acc2[0][0].x, acc2[0][1].x, acc2[0][2].x, acc2[0][3].x);
    *reinterpret_cast<float4*>(op + 1 * WW) =
        make_float4(acc2[0][0].y, acc2[0][1].y, acc2[0][2].y, acc2[0][3].y);
    *reinterpret_cast<float4*>(op + 2 * WW) =
        make_float4(acc2[1][0].x, acc2[1][1].x, acc2[1][2].x, acc2[1][3].x);
    *reinterpret_cast<float4*>(op + 3 * WW) =
        make_float4(acc2[1][0].y, acc2[1][1].y, acc2[1][2].y, acc2[1][3].y);
}

extern "C" void kernel_launch(void* const* d_in, const int* in_sizes, int n_in,
                              void* d_out, int out_size, void* d_ws, size_t ws_size,
                              hipStream_t stream)
{
    const float* imgs = (const float*)d_in[0];
    const float* kern = (const float*)d_in[1];
    float* out = (float*)d_out;

    const int blocks = BB * CC * (HH / TR);   // 4096
    selconv_kernel<<<blocks, 256, 0, stream>>>(imgs, kern, out);
}